// Round 1
// baseline (30.673 us; speedup 1.0000x reference)
//
#include <hip/hip_runtime.h>
#include <hip/hip_bf16.h>

#define VOCAB   32000
#define DIM     5120
#define VDIM    768
#define BATCH   2
#define TLEN    512
#define TVIS    32
#define NSTATIC (VOCAB + 2)          // 32002
#define NROWS   (BATCH * TVIS)       // 64 vision rows total

typedef __attribute__((ext_vector_type(8))) short short8_t;
typedef __attribute__((ext_vector_type(4))) float floatx4;

// ---------------------------------------------------------------------------
// Kernel A: vis[r][d] = sum_v vf[r][v] * fcw[d][v] + fcb[d]
//   r = b*TVIS + tv (64 rows), d in [0, 5120)
// grid = DIM/16 = 320 blocks, 256 threads (4 waves).
// Each block: C tile [64 rows x 16 d], full K=768 in one LDS load.
// f32 -> bf16 conversion fused into staging (fc_w touched exactly once).
// ---------------------------------------------------------------------------
__global__ __launch_bounds__(256) void vis_proj_kernel(
    const float* __restrict__ vf,    // [64][768]
    const float* __restrict__ fcw,   // [5120][768]
    const float* __restrict__ fcb,   // [5120]
    float* __restrict__ vis)         // [64][5120] (workspace)
{
    constexpr int KP = VDIM + 8;     // padded LDS stride (bf16 elems) = 776
    __shared__ __hip_bfloat16 sX[NROWS * KP];  // 99.3 KB
    __shared__ __hip_bfloat16 sW[16 * KP];     // 24.8 KB
    const int tid = threadIdx.x;
    const int d0  = blockIdx.x * 16;

    // stage X: 64x768 f32 -> bf16, 8 elems (32B global) per thread-iter
    for (int i = tid; i < NROWS * (VDIM / 8); i += 256) {
        const int row = i / (VDIM / 8);
        const int kc  = (i % (VDIM / 8)) * 8;
        const float4 f0 = *reinterpret_cast<const float4*>(&vf[row * VDIM + kc]);
        const float4 f1 = *reinterpret_cast<const float4*>(&vf[row * VDIM + kc + 4]);
        union { __hip_bfloat16 h[8]; short8_t v; } u;
        u.h[0] = __float2bfloat16(f0.x); u.h[1] = __float2bfloat16(f0.y);
        u.h[2] = __float2bfloat16(f0.z); u.h[3] = __float2bfloat16(f0.w);
        u.h[4] = __float2bfloat16(f1.x); u.h[5] = __float2bfloat16(f1.y);
        u.h[6] = __float2bfloat16(f1.z); u.h[7] = __float2bfloat16(f1.w);
        *reinterpret_cast<short8_t*>(&sX[row * KP + kc]) = u.v;
    }
    // stage W tile: 16 rows of fc_w
    for (int i = tid; i < 16 * (VDIM / 8); i += 256) {
        const int row = i / (VDIM / 8);
        const int kc  = (i % (VDIM / 8)) * 8;
        const float* g = &fcw[(size_t)(d0 + row) * VDIM + kc];
        const float4 f0 = *reinterpret_cast<const float4*>(g);
        const float4 f1 = *reinterpret_cast<const float4*>(g + 4);
        union { __hip_bfloat16 h[8]; short8_t v; } u;
        u.h[0] = __float2bfloat16(f0.x); u.h[1] = __float2bfloat16(f0.y);
        u.h[2] = __float2bfloat16(f0.z); u.h[3] = __float2bfloat16(f0.w);
        u.h[4] = __float2bfloat16(f1.x); u.h[5] = __float2bfloat16(f1.y);
        u.h[6] = __float2bfloat16(f1.z); u.h[7] = __float2bfloat16(f1.w);
        *reinterpret_cast<short8_t*>(&sW[row * KP + kc]) = u.v;
    }
    __syncthreads();

    const int wave = tid >> 6;       // m-tile (16 rows each)
    const int lane = tid & 63;
    const int l15  = lane & 15;
    const int lhi  = lane >> 4;

    floatx4 acc = {0.f, 0.f, 0.f, 0.f};
    const __hip_bfloat16* ax = &sX[(wave * 16 + l15) * KP + lhi * 8];
    const __hip_bfloat16* bx = &sW[l15 * KP + lhi * 8];
#pragma unroll
    for (int k0 = 0; k0 < VDIM; k0 += 32) {
        short8_t a = *reinterpret_cast<const short8_t*>(ax + k0);
        short8_t b = *reinterpret_cast<const short8_t*>(bx + k0);
        acc = __builtin_amdgcn_mfma_f32_16x16x32_bf16(a, b, acc, 0, 0, 0);
    }

    // C/D layout: col = lane&15 (n -> d), row = (lane>>4)*4 + reg (m -> r)
    const int   d    = d0 + l15;
    const float bias = fcb[d];
#pragma unroll
    for (int r = 0; r < 4; ++r) {
        const int m = wave * 16 + lhi * 4 + r;
        vis[(size_t)m * DIM + d] = acc[r] + bias;
    }
}

// ---------------------------------------------------------------------------
// Kernel B: per-token row gather. One block per (b,t) token.
//   idx <  32002 -> weight / figure_token_weight row
//   idx >= 32002 -> vis[b][min(idx-32002, 31)] row from workspace
// ---------------------------------------------------------------------------
__global__ __launch_bounds__(256) void gather_kernel(
    const int*   __restrict__ text,   // [1024]
    const float* __restrict__ weight, // [32000][5120]
    const float* __restrict__ fig,    // [2][5120]
    const float* __restrict__ vis,    // [64][5120]
    float*       __restrict__ out)    // [1024][5120]
{
    const int bt  = blockIdx.x;
    const int b   = bt / TLEN;
    const int idx = text[bt];

    const float* src;
    if (idx < NSTATIC) {
        int r = idx < 0 ? 0 : idx;            // clip low (matches jnp.clip)
        src = (r < VOCAB) ? &weight[(size_t)r * DIM]
                          : &fig[(size_t)(r - VOCAB) * DIM];
    } else {
        int vr = idx - NSTATIC;
        if (vr > TVIS - 1) vr = TVIS - 1;     // clip high (matches jnp.clip)
        src = &vis[(size_t)(b * TVIS + vr) * DIM];
    }

    float*       dst = &out[(size_t)bt * DIM];
    const float4* s4 = reinterpret_cast<const float4*>(src);
    float4*       d4 = reinterpret_cast<float4*>(dst);
#pragma unroll
    for (int i = threadIdx.x; i < DIM / 4; i += 256) {
        d4[i] = s4[i];
    }
}

extern "C" void kernel_launch(void* const* d_in, const int* in_sizes, int n_in,
                              void* d_out, int out_size, void* d_ws, size_t ws_size,
                              hipStream_t stream) {
    (void)in_sizes; (void)n_in; (void)out_size; (void)ws_size;
    const int*   text = (const int*)  d_in[0];  // (B,T) int32
    const float* vf   = (const float*)d_in[1];  // (B,TV,VD)
    const float* w    = (const float*)d_in[2];  // (V,D)
    const float* fig  = (const float*)d_in[3];  // (2,D)
    const float* fcw  = (const float*)d_in[4];  // (D,VD)
    const float* fcb  = (const float*)d_in[5];  // (D,)
    float* out = (float*)d_out;                 // (B,T,D) f32
    float* vis = (float*)d_ws;                  // 64*5120*4 = 1.31 MB scratch

    vis_proj_kernel<<<DIM / 16, 256, 0, stream>>>(vf, fcw, fcb, vis);
    gather_kernel<<<BATCH * TLEN, 256, 0, stream>>>(text, w, fig, vis, out);
}

// Round 2
// 27.884 us; speedup vs baseline: 1.1000x; 1.1000x over previous
//
#include <hip/hip_runtime.h>
#include <hip/hip_bf16.h>

#define VOCAB   32000
#define DIM     5120
#define VDIM    768
#define BATCH   2
#define TLEN    512
#define TVIS    32
#define NSTATIC (VOCAB + 2)          // 32002
#define NROWS   (BATCH * TVIS)       // 64 vision rows total

typedef __attribute__((ext_vector_type(8))) short short8_t;
typedef __attribute__((ext_vector_type(4))) float floatx4;

// load 8 consecutive f32 and convert to a bf16x8 MFMA fragment
__device__ __forceinline__ short8_t cvt8(const float* __restrict__ p) {
    const float4 f0 = *reinterpret_cast<const float4*>(p);
    const float4 f1 = *reinterpret_cast<const float4*>(p + 4);
    union { __hip_bfloat16 h[8]; short8_t v; } u;
    u.h[0] = __float2bfloat16(f0.x); u.h[1] = __float2bfloat16(f0.y);
    u.h[2] = __float2bfloat16(f0.z); u.h[3] = __float2bfloat16(f0.w);
    u.h[4] = __float2bfloat16(f1.x); u.h[5] = __float2bfloat16(f1.y);
    u.h[6] = __float2bfloat16(f1.z); u.h[7] = __float2bfloat16(f1.w);
    return u.v;
}

// ---------------------------------------------------------------------------
// Kernel A: vis[r][d] = sum_v vf[r][v] * fcw[d][v] + fcb[d]
// No LDS staging: fc_w has zero reuse (each d read by exactly one block) and
// vf (196 KB) is L2-resident. Stream both straight into MFMA fragments with
// in-register f32->bf16 convert. K split across the 4 waves (192 each) for
// 4x wave parallelism; partials reduced via a small padded-LDS buffer.
// grid = DIM/16 = 320 blocks x 256 threads.
// ---------------------------------------------------------------------------
__global__ __launch_bounds__(256) void vis_proj_kernel(
    const float* __restrict__ vf,    // [64][768]
    const float* __restrict__ fcw,   // [5120][768]
    const float* __restrict__ fcb,   // [5120]
    float* __restrict__ vis)         // [64][5120] (workspace)
{
    __shared__ float sAcc[4][NROWS][17];     // +1 pad -> 2-way banks (free)

    const int tid  = threadIdx.x;
    const int wave = tid >> 6;
    const int lane = tid & 63;
    const int l15  = lane & 15;
    const int lhi  = lane >> 4;
    const int d0   = blockIdx.x * 16;

    // wave's K range: [wave*192, wave*192+192), fragment k-offset lhi*8
    const int kbase = wave * 192 + lhi * 8;
    const float* wrow  = &fcw[(size_t)(d0 + l15) * VDIM + kbase]; // HBM stream
    const float* xbase = &vf[(size_t)l15 * VDIM + kbase];         // L2-resident

    floatx4 acc[4];
#pragma unroll
    for (int mi = 0; mi < 4; ++mi) acc[mi] = floatx4{0.f, 0.f, 0.f, 0.f};

#pragma unroll
    for (int j = 0; j < 6; ++j) {            // 6 chunks of k-32
        const short8_t b = cvt8(wrow + j * 32);
#pragma unroll
        for (int mi = 0; mi < 4; ++mi) {     // 4 m-subtiles cover 64 rows
            const short8_t a = cvt8(xbase + (size_t)mi * 16 * VDIM + j * 32);
            acc[mi] = __builtin_amdgcn_mfma_f32_16x16x32_bf16(a, b, acc[mi], 0, 0, 0);
        }
    }

    // C/D layout: col = lane&15 (-> d), row = (lane>>4)*4 + reg (-> r)
#pragma unroll
    for (int mi = 0; mi < 4; ++mi)
#pragma unroll
        for (int r = 0; r < 4; ++r)
            sAcc[wave][mi * 16 + lhi * 4 + r][l15] = acc[mi][r];
    __syncthreads();

    // reduce the 4 K-partials, add bias, store
#pragma unroll
    for (int o = tid; o < NROWS * 16; o += 256) {
        const int r = o >> 4;
        const int d = o & 15;
        const float s = sAcc[0][r][d] + sAcc[1][r][d] +
                        sAcc[2][r][d] + sAcc[3][r][d] + fcb[d0 + d];
        vis[(size_t)r * DIM + d0 + d] = s;
    }
}

// ---------------------------------------------------------------------------
// Kernel B: per-token row gather. One block per (b,t) token.
//   idx <  32002 -> weight / figure_token_weight row
//   idx >= 32002 -> vis[b][min(idx-32002, 31)] row from workspace
// ---------------------------------------------------------------------------
__global__ __launch_bounds__(256) void gather_kernel(
    const int*   __restrict__ text,   // [1024]
    const float* __restrict__ weight, // [32000][5120]
    const float* __restrict__ fig,    // [2][5120]
    const float* __restrict__ vis,    // [64][5120]
    float*       __restrict__ out)    // [1024][5120]
{
    const int bt  = blockIdx.x;
    const int b   = bt / TLEN;
    const int idx = text[bt];

    const float* src;
    if (idx < NSTATIC) {
        int r = idx < 0 ? 0 : idx;            // clip low (matches jnp.clip)
        src = (r < VOCAB) ? &weight[(size_t)r * DIM]
                          : &fig[(size_t)(r - VOCAB) * DIM];
    } else {
        int vr = idx - NSTATIC;
        if (vr > TVIS - 1) vr = TVIS - 1;     // clip high (matches jnp.clip)
        src = &vis[(size_t)(b * TVIS + vr) * DIM];
    }

    float*       dst = &out[(size_t)bt * DIM];
    const float4* s4 = reinterpret_cast<const float4*>(src);
    float4*       d4 = reinterpret_cast<float4*>(dst);
#pragma unroll
    for (int i = threadIdx.x; i < DIM / 4; i += 256) {
        d4[i] = s4[i];
    }
}

extern "C" void kernel_launch(void* const* d_in, const int* in_sizes, int n_in,
                              void* d_out, int out_size, void* d_ws, size_t ws_size,
                              hipStream_t stream) {
    (void)in_sizes; (void)n_in; (void)out_size; (void)ws_size;
    const int*   text = (const int*)  d_in[0];  // (B,T) int32
    const float* vf   = (const float*)d_in[1];  // (B,TV,VD)
    const float* w    = (const float*)d_in[2];  // (V,D)
    const float* fig  = (const float*)d_in[3];  // (2,D)
    const float* fcw  = (const float*)d_in[4];  // (D,VD)
    const float* fcb  = (const float*)d_in[5];  // (D,)
    float* out = (float*)d_out;                 // (B,T,D) f32
    float* vis = (float*)d_ws;                  // 64*5120*4 = 1.31 MB scratch

    vis_proj_kernel<<<DIM / 16, 256, 0, stream>>>(vf, fcw, fcb, vis);
    gather_kernel<<<BATCH * TLEN, 256, 0, stream>>>(text, w, fig, vis, out);
}

// Round 3
// 25.785 us; speedup vs baseline: 1.1896x; 1.0814x over previous
//
#include <hip/hip_runtime.h>
#include <hip/hip_bf16.h>

#define VOCAB   32000
#define DIM     5120
#define VDIM    768
#define BATCH   2
#define TLEN    512
#define TVIS    32
#define NSTATIC (VOCAB + 2)          // 32002
#define NROWS   (BATCH * TVIS)       // 64 vision rows total
#define NPROJ   (DIM / 16)           // 320 projection blocks

typedef __attribute__((ext_vector_type(8))) short short8_t;
typedef __attribute__((ext_vector_type(4))) float floatx4;

// load 8 consecutive f32 and convert to a bf16x8 MFMA fragment
__device__ __forceinline__ short8_t cvt8(const float* __restrict__ p) {
    const float4 f0 = *reinterpret_cast<const float4*>(p);
    const float4 f1 = *reinterpret_cast<const float4*>(p + 4);
    union { __hip_bfloat16 h[8]; short8_t v; } u;
    u.h[0] = __float2bfloat16(f0.x); u.h[1] = __float2bfloat16(f0.y);
    u.h[2] = __float2bfloat16(f0.z); u.h[3] = __float2bfloat16(f0.w);
    u.h[4] = __float2bfloat16(f1.x); u.h[5] = __float2bfloat16(f1.y);
    u.h[6] = __float2bfloat16(f1.z); u.h[7] = __float2bfloat16(f1.w);
    return u.v;
}

// ---------------------------------------------------------------------------
// Kernel 1: one grid, two independent roles (no inter-block dependency).
//   blocks [0, 320):    vis[r][d0..d0+16) = vf @ fcw^T + fcb   (MFMA, K-split)
//   blocks [320, 1344): out[bt] = static table row (vision tokens skipped)
// The proj's fc_w stream overlaps the gather's weight stream in one dispatch.
// ---------------------------------------------------------------------------
__global__ __launch_bounds__(256) void fused_kernel(
    const int*   __restrict__ text,   // [1024]
    const float* __restrict__ vf,     // [64][768]
    const float* __restrict__ fcw,    // [5120][768]
    const float* __restrict__ fcb,    // [5120]
    const float* __restrict__ weight, // [32000][5120]
    const float* __restrict__ fig,    // [2][5120]
    float*       __restrict__ vis,    // [64][5120] (workspace)
    float*       __restrict__ out)    // [1024][5120]
{
    __shared__ float sAcc[4][NROWS][17];     // +1 pad -> 2-way banks (free)
    const int tid = threadIdx.x;

    if (blockIdx.x < NPROJ) {
        // ---- projection role ----
        const int wave = tid >> 6;
        const int lane = tid & 63;
        const int l15  = lane & 15;
        const int lhi  = lane >> 4;
        const int d0   = blockIdx.x * 16;

        const int kbase = wave * 192 + lhi * 8;
        const float* wrow  = &fcw[(size_t)(d0 + l15) * VDIM + kbase];
        const float* xbase = &vf[(size_t)l15 * VDIM + kbase];

        floatx4 acc[4];
#pragma unroll
        for (int mi = 0; mi < 4; ++mi) acc[mi] = floatx4{0.f, 0.f, 0.f, 0.f};

#pragma unroll
        for (int j = 0; j < 6; ++j) {            // 6 chunks of k-32
            const short8_t b = cvt8(wrow + j * 32);
#pragma unroll
            for (int mi = 0; mi < 4; ++mi) {     // 4 m-subtiles cover 64 rows
                const short8_t a = cvt8(xbase + (size_t)mi * 16 * VDIM + j * 32);
                acc[mi] = __builtin_amdgcn_mfma_f32_16x16x32_bf16(a, b, acc[mi], 0, 0, 0);
            }
        }

        // C/D layout: col = lane&15 (-> d), row = (lane>>4)*4 + reg (-> r)
#pragma unroll
        for (int mi = 0; mi < 4; ++mi)
#pragma unroll
            for (int r = 0; r < 4; ++r)
                sAcc[wave][mi * 16 + lhi * 4 + r][l15] = acc[mi][r];
        __syncthreads();

#pragma unroll
        for (int o = tid; o < NROWS * 16; o += 256) {
            const int r = o >> 4;
            const int d = o & 15;
            const float s = sAcc[0][r][d] + sAcc[1][r][d] +
                            sAcc[2][r][d] + sAcc[3][r][d] + fcb[d0 + d];
            vis[(size_t)r * DIM + d0 + d] = s;
        }
    } else {
        // ---- static-token gather role ----
        const int bt  = blockIdx.x - NPROJ;
        const int idx = text[bt];
        if (idx >= NSTATIC) return;               // vision token: kernel 2 fixes up

        int r = idx < 0 ? 0 : idx;                // clip low (matches jnp.clip)
        const float* src = (r < VOCAB) ? &weight[(size_t)r * DIM]
                                       : &fig[(size_t)(r - VOCAB) * DIM];
        const float4* s4 = reinterpret_cast<const float4*>(src);
        float4*       d4 = reinterpret_cast<float4*>(&out[(size_t)bt * DIM]);
#pragma unroll
        for (int i = tid; i < DIM / 4; i += 256) {
            d4[i] = s4[i];
        }
    }
}

// ---------------------------------------------------------------------------
// Kernel 2: vision-token fixup. ~1 of 1024 blocks does a 20 KB L2-resident
// row copy; the rest load one int and exit.
// ---------------------------------------------------------------------------
__global__ __launch_bounds__(256) void vis_fixup_kernel(
    const int*   __restrict__ text,   // [1024]
    const float* __restrict__ vis,    // [64][5120]
    float*       __restrict__ out)    // [1024][5120]
{
    const int bt  = blockIdx.x;
    const int idx = text[bt];
    if (idx < NSTATIC) return;

    const int b  = bt / TLEN;
    int vr = idx - NSTATIC;
    if (vr > TVIS - 1) vr = TVIS - 1;             // clip high (matches jnp.clip)

    const float4* s4 = reinterpret_cast<const float4*>(&vis[(size_t)(b * TVIS + vr) * DIM]);
    float4*       d4 = reinterpret_cast<float4*>(&out[(size_t)bt * DIM]);
#pragma unroll
    for (int i = threadIdx.x; i < DIM / 4; i += 256) {
        d4[i] = s4[i];
    }
}

extern "C" void kernel_launch(void* const* d_in, const int* in_sizes, int n_in,
                              void* d_out, int out_size, void* d_ws, size_t ws_size,
                              hipStream_t stream) {
    (void)in_sizes; (void)n_in; (void)out_size; (void)ws_size;
    const int*   text = (const int*)  d_in[0];  // (B,T) int32
    const float* vf   = (const float*)d_in[1];  // (B,TV,VD)
    const float* w    = (const float*)d_in[2];  // (V,D)
    const float* fig  = (const float*)d_in[3];  // (2,D)
    const float* fcw  = (const float*)d_in[4];  // (D,VD)
    const float* fcb  = (const float*)d_in[5];  // (D,)
    float* out = (float*)d_out;                 // (B,T,D) f32
    float* vis = (float*)d_ws;                  // 64*5120*4 = 1.31 MB scratch

    fused_kernel<<<NPROJ + BATCH * TLEN, 256, 0, stream>>>(
        text, vf, fcw, fcb, w, fig, vis, out);
    vis_fixup_kernel<<<BATCH * TLEN, 256, 0, stream>>>(text, vis, out);
}

// Round 4
// 23.619 us; speedup vs baseline: 1.2987x; 1.0917x over previous
//
#include <hip/hip_runtime.h>
#include <hip/hip_bf16.h>

#define VOCAB   32000
#define DIM     5120
#define VDIM    768
#define BATCH   2
#define TLEN    512
#define NTOK    (BATCH * TLEN)       // 1024 tokens
#define TVIS    32
#define NSTATIC (VOCAB + 2)          // 32002
#define NROWS   (BATCH * TVIS)       // 64 vision rows total
#define NPROJ   (DIM / 16)           // 320 projection blocks

typedef __attribute__((ext_vector_type(8))) short short8_t;
typedef __attribute__((ext_vector_type(4))) float floatx4;

// load 8 consecutive f32 and convert to a bf16x8 MFMA fragment
__device__ __forceinline__ short8_t cvt8(const float* __restrict__ p) {
    const float4 f0 = *reinterpret_cast<const float4*>(p);
    const float4 f1 = *reinterpret_cast<const float4*>(p + 4);
    union { __hip_bfloat16 h[8]; short8_t v; } u;
    u.h[0] = __float2bfloat16(f0.x); u.h[1] = __float2bfloat16(f0.y);
    u.h[2] = __float2bfloat16(f0.z); u.h[3] = __float2bfloat16(f0.w);
    u.h[4] = __float2bfloat16(f1.x); u.h[5] = __float2bfloat16(f1.y);
    u.h[6] = __float2bfloat16(f1.z); u.h[7] = __float2bfloat16(f1.w);
    return u.v;
}

// ---------------------------------------------------------------------------
// Single kernel, two independent roles, no workspace, no second dispatch.
//   blocks [0, 320):    proj role. Compute the 64-row x 16-col tile of
//                       vf @ fcw^T + fcb in LDS, then scan the 1024 token ids
//                       and write out[bt][d0..d0+16) for every VISION token.
//                       (320 blocks collectively cover all 5120 columns.)
//   blocks [320, 1344): gather role. out[bt] = static table row; vision
//                       tokens are skipped (proj role owns them).
// No inter-block dependency -> safe in one dispatch; proj's fc_w stream
// overlaps the gather's weight stream.
// ---------------------------------------------------------------------------
__global__ __launch_bounds__(256) void fused_kernel(
    const int*   __restrict__ text,   // [1024]
    const float* __restrict__ vf,     // [64][768]
    const float* __restrict__ fcw,    // [5120][768]
    const float* __restrict__ fcb,    // [5120]
    const float* __restrict__ weight, // [32000][5120]
    const float* __restrict__ fig,    // [2][5120]
    float*       __restrict__ out)    // [1024][5120]
{
    __shared__ float sAcc[4][NROWS][17];     // +1 pad -> 2-way banks (free)
    const int tid = threadIdx.x;

    if (blockIdx.x < NPROJ) {
        // ---- projection role ----
        const int wave = tid >> 6;
        const int lane = tid & 63;
        const int l15  = lane & 15;
        const int lhi  = lane >> 4;
        const int d0   = blockIdx.x * 16;

        // wave's K range: [wave*192, wave*192+192), fragment k-offset lhi*8
        const int kbase = wave * 192 + lhi * 8;
        const float* wrow  = &fcw[(size_t)(d0 + l15) * VDIM + kbase]; // HBM
        const float* xbase = &vf[(size_t)l15 * VDIM + kbase];         // L2

        floatx4 acc[4];
#pragma unroll
        for (int mi = 0; mi < 4; ++mi) acc[mi] = floatx4{0.f, 0.f, 0.f, 0.f};

#pragma unroll
        for (int j = 0; j < 6; ++j) {            // 6 chunks of k-32
            const short8_t b = cvt8(wrow + j * 32);
#pragma unroll
            for (int mi = 0; mi < 4; ++mi) {     // 4 m-subtiles cover 64 rows
                const short8_t a = cvt8(xbase + (size_t)mi * 16 * VDIM + j * 32);
                acc[mi] = __builtin_amdgcn_mfma_f32_16x16x32_bf16(a, b, acc[mi], 0, 0, 0);
            }
        }

        // C/D layout: col = lane&15 (-> d), row = (lane>>4)*4 + reg (-> r)
#pragma unroll
        for (int mi = 0; mi < 4; ++mi)
#pragma unroll
            for (int r = 0; r < 4; ++r)
                sAcc[wave][mi * 16 + lhi * 4 + r][l15] = acc[mi][r];
        __syncthreads();

        // reduce K-partials + bias into sAcc[0]
#pragma unroll
        for (int o = tid; o < NROWS * 16; o += 256) {
            const int r = o >> 4;
            const int d = o & 15;
            sAcc[0][r][d] = sAcc[0][r][d] + sAcc[1][r][d] +
                            sAcc[2][r][d] + sAcc[3][r][d] + fcb[d0 + d];
        }
        __syncthreads();

        // scan token ids; write our 16 columns for every vision token
        for (int t = tid; t < NTOK; t += 256) {
            const int idx = text[t];
            if (idx < NSTATIC) continue;
            int vr = idx - NSTATIC;
            if (vr > TVIS - 1) vr = TVIS - 1;     // clip high (matches jnp.clip)
            const int r = (t / TLEN) * TVIS + vr;
            float* dst = &out[(size_t)t * DIM + d0];
#pragma unroll
            for (int d = 0; d < 16; ++d) dst[d] = sAcc[0][r][d];
        }
    } else {
        // ---- static-token gather role ----
        const int bt  = blockIdx.x - NPROJ;
        const int idx = text[bt];
        if (idx >= NSTATIC) return;               // vision token: proj role owns it

        int r = idx < 0 ? 0 : idx;                // clip low (matches jnp.clip)
        const float* src = (r < VOCAB) ? &weight[(size_t)r * DIM]
                                       : &fig[(size_t)(r - VOCAB) * DIM];
        const float4* s4 = reinterpret_cast<const float4*>(src);
        float4*       d4 = reinterpret_cast<float4*>(&out[(size_t)bt * DIM]);
#pragma unroll
        for (int i = tid; i < DIM / 4; i += 256) {
            d4[i] = s4[i];
        }
    }
}

extern "C" void kernel_launch(void* const* d_in, const int* in_sizes, int n_in,
                              void* d_out, int out_size, void* d_ws, size_t ws_size,
                              hipStream_t stream) {
    (void)in_sizes; (void)n_in; (void)out_size; (void)d_ws; (void)ws_size;
    const int*   text = (const int*)  d_in[0];  // (B,T) int32
    const float* vf   = (const float*)d_in[1];  // (B,TV,VD)
    const float* w    = (const float*)d_in[2];  // (V,D)
    const float* fig  = (const float*)d_in[3];  // (2,D)
    const float* fcw  = (const float*)d_in[4];  // (D,VD)
    const float* fcb  = (const float*)d_in[5];  // (D,)
    float* out = (float*)d_out;                 // (B,T,D) f32

    fused_kernel<<<NPROJ + NTOK, 256, 0, stream>>>(
        text, vf, fcw, fcb, w, fig, out);
}

// Round 6
// 20.035 us; speedup vs baseline: 1.5310x; 1.1789x over previous
//
#include <hip/hip_runtime.h>
#include <hip/hip_bf16.h>

#define VOCAB   32000
#define DIM     5120
#define VDIM    768
#define BATCH   2
#define TLEN    512
#define NTOK    (BATCH * TLEN)       // 1024 tokens
#define TVIS    32
#define NSTATIC (VOCAB + 2)          // 32002
#define NROWS   (BATCH * TVIS)       // 64 possible vision rows
#define NPROJ   (DIM / 16)           // 320 projection blocks

typedef __attribute__((ext_vector_type(8))) short short8_t;
typedef __attribute__((ext_vector_type(4))) float floatx4;

// load 8 consecutive f32 (nontemporal: zero-reuse stream) -> bf16x8 fragment
__device__ __forceinline__ short8_t cvt8_nt(const float* __restrict__ p) {
    const floatx4 f0 = __builtin_nontemporal_load(reinterpret_cast<const floatx4*>(p));
    const floatx4 f1 = __builtin_nontemporal_load(reinterpret_cast<const floatx4*>(p) + 1);
    union { __hip_bfloat16 h[8]; short8_t v; } u;
    u.h[0] = __float2bfloat16(f0.x); u.h[1] = __float2bfloat16(f0.y);
    u.h[2] = __float2bfloat16(f0.z); u.h[3] = __float2bfloat16(f0.w);
    u.h[4] = __float2bfloat16(f1.x); u.h[5] = __float2bfloat16(f1.y);
    u.h[6] = __float2bfloat16(f1.z); u.h[7] = __float2bfloat16(f1.w);
    return u.v;
}
// cached variant (vf is reused across blocks -> keep in L2)
__device__ __forceinline__ short8_t cvt8(const float* __restrict__ p) {
    const floatx4 f0 = *reinterpret_cast<const floatx4*>(p);
    const floatx4 f1 = *reinterpret_cast<const floatx4*>(p + 4);
    union { __hip_bfloat16 h[8]; short8_t v; } u;
    u.h[0] = __float2bfloat16(f0.x); u.h[1] = __float2bfloat16(f0.y);
    u.h[2] = __float2bfloat16(f0.z); u.h[3] = __float2bfloat16(f0.w);
    u.h[4] = __float2bfloat16(f1.x); u.h[5] = __float2bfloat16(f1.y);
    u.h[6] = __float2bfloat16(f1.z); u.h[7] = __float2bfloat16(f1.w);
    return u.v;
}

// ---------------------------------------------------------------------------
// Single kernel, two roles, one dispatch, no workspace.
//   blocks [0, 320):    proj role. Scan text, compact the REFERENCED vision
//                       rows (typically ~1 of 64), compute only those rows'
//                       projection for this block's 16 columns, write them.
//                       cnt==0 -> skip the fc_w stream entirely.
//   blocks [320, 1344): gather role. out[bt] = static table row (nontemporal
//                       streams); vision tokens skipped (proj role owns them).
// ---------------------------------------------------------------------------
__global__ __launch_bounds__(256) void fused_kernel(
    const int*   __restrict__ text,   // [1024]
    const float* __restrict__ vf,     // [64][768]
    const float* __restrict__ fcw,    // [5120][768]
    const float* __restrict__ fcb,    // [5120]
    const float* __restrict__ weight, // [32000][5120]
    const float* __restrict__ fig,    // [2][5120]
    float*       __restrict__ out)    // [1024][5120]
{
    const int tid = threadIdx.x;

    if (blockIdx.x < NPROJ) {
        // ---- projection role ----
        __shared__ float sAcc[4][NROWS][17];      // +1 pad -> 2-way banks (free)
        __shared__ unsigned needMask[2];          // bitmap of needed rows
        __shared__ unsigned char rowList[NROWS];  // compacted slot -> row
        __shared__ unsigned char slotOf[NROWS];   // row -> slot
        __shared__ int visTok[NTOK];              // (t<<6)|r per vision token
        __shared__ int cntSh, nvSh;

        if (tid < 2) needMask[tid] = 0u;
        if (tid == 0) nvSh = 0;
        __syncthreads();

        // scan token ids: mark needed rows, append vision-token list
        for (int t = tid; t < NTOK; t += 256) {
            const int idx = text[t];
            if (idx >= NSTATIC) {
                int vr = idx - NSTATIC;
                if (vr > TVIS - 1) vr = TVIS - 1;     // clip high (jnp.clip)
                const int r = (t >> 9) * TVIS + vr;   // b*32 + vr
                atomicOr(&needMask[r >> 5], 1u << (r & 31));
                visTok[atomicAdd(&nvSh, 1)] = (t << 6) | r;
            }
        }
        __syncthreads();
        if (tid == 0) {
            int c = 0;
            for (int r = 0; r < NROWS; ++r)
                if (needMask[r >> 5] & (1u << (r & 31))) {
                    rowList[c] = (unsigned char)r;
                    slotOf[r]  = (unsigned char)c;
                    ++c;
                }
            cntSh = c;
        }
        __syncthreads();
        const int cnt = cntSh;
        if (cnt == 0) return;                     // no vision tokens at all

        const int wave = tid >> 6;
        const int lane = tid & 63;
        const int l15  = lane & 15;
        const int lhi  = lane >> 4;
        const int d0   = blockIdx.x * 16;
        const int ngrp = (cnt + 15) >> 4;         // 16-row MFMA groups (<=4)

        // wave's K range: [wave*192, +192), fragment k-offset lhi*8
        const int kbase = wave * 192 + lhi * 8;
        const float* wrow = &fcw[(size_t)(d0 + l15) * VDIM + kbase]; // HBM stream

        int myrow[4];
#pragma unroll
        for (int g = 0; g < 4; ++g) {
            const int s = g * 16 + l15;
            myrow[g] = rowList[s < cnt ? s : 0];
        }

        floatx4 acc[4];
#pragma unroll
        for (int g = 0; g < 4; ++g) acc[g] = floatx4{0.f, 0.f, 0.f, 0.f};

#pragma unroll
        for (int j = 0; j < 6; ++j) {             // 6 chunks of k-32
            const short8_t b = cvt8_nt(wrow + j * 32);
#pragma unroll
            for (int g = 0; g < 4; ++g) {         // block-uniform guard
                if (g < ngrp) {
                    const short8_t a = cvt8(&vf[(size_t)myrow[g] * VDIM + kbase + j * 32]);
                    acc[g] = __builtin_amdgcn_mfma_f32_16x16x32_bf16(a, b, acc[g], 0, 0, 0);
                }
            }
        }

        // C/D layout: col = lane&15 (-> d), row = (lane>>4)*4 + reg (-> slot)
#pragma unroll
        for (int g = 0; g < 4; ++g)
            if (g < ngrp)
#pragma unroll
                for (int rr = 0; rr < 4; ++rr)
                    sAcc[wave][g * 16 + lhi * 4 + rr][l15] = acc[g][rr];
        __syncthreads();

        // reduce K-partials + bias for live slots
        for (int o = tid; o < cnt * 16; o += 256) {
            const int s = o >> 4;
            const int d = o & 15;
            sAcc[0][s][d] = sAcc[0][s][d] + sAcc[1][s][d] +
                            sAcc[2][s][d] + sAcc[3][s][d] + fcb[d0 + d];
        }
        __syncthreads();

        // write our 16 columns for each vision token (16 threads per token)
        const int nv = nvSh;
        for (int e = tid >> 4; e < nv; e += 16) {
            const int pk = visTok[e];
            const int t  = pk >> 6;
            const int s  = slotOf[pk & 63];
            out[(size_t)t * DIM + d0 + (tid & 15)] = sAcc[0][s][tid & 15];
        }
    } else {
        // ---- static-token gather role ----
        const int bt  = blockIdx.x - NPROJ;
        const int idx = text[bt];
        if (idx >= NSTATIC) return;               // vision token: proj role owns it

        int r = idx < 0 ? 0 : idx;                // clip low (matches jnp.clip)
        const float* src = (r < VOCAB) ? &weight[(size_t)r * DIM]
                                       : &fig[(size_t)(r - VOCAB) * DIM];
        const floatx4* s4 = reinterpret_cast<const floatx4*>(src);
        floatx4*       d4 = reinterpret_cast<floatx4*>(&out[(size_t)bt * DIM]);
#pragma unroll
        for (int i = tid; i < DIM / 4; i += 256) {
            const floatx4 v = __builtin_nontemporal_load(&s4[i]);
            __builtin_nontemporal_store(v, &d4[i]);
        }
    }
}

extern "C" void kernel_launch(void* const* d_in, const int* in_sizes, int n_in,
                              void* d_out, int out_size, void* d_ws, size_t ws_size,
                              hipStream_t stream) {
    (void)in_sizes; (void)n_in; (void)out_size; (void)d_ws; (void)ws_size;
    const int*   text = (const int*)  d_in[0];  // (B,T) int32
    const float* vf   = (const float*)d_in[1];  // (B,TV,VD)
    const float* w    = (const float*)d_in[2];  // (V,D)
    const float* fig  = (const float*)d_in[3];  // (2,D)
    const float* fcw  = (const float*)d_in[4];  // (D,VD)
    const float* fcb  = (const float*)d_in[5];  // (D,)
    float* out = (float*)d_out;                 // (B,T,D) f32

    fused_kernel<<<NPROJ + NTOK, 256, 0, stream>>>(
        text, vf, fcw, fcb, w, fig, out);
}

// Round 7
// 17.613 us; speedup vs baseline: 1.7415x; 1.1375x over previous
//
#include <hip/hip_runtime.h>
#include <hip/hip_bf16.h>

#define VOCAB   32000
#define DIM     5120
#define VDIM    768
#define BATCH   2
#define TLEN    512
#define NTOK    (BATCH * TLEN)       // 1024 tokens
#define TVIS    32
#define NSTATIC (VOCAB + 2)          // 32002
#define NROWS   (BATCH * TVIS)       // 64 possible vision rows
#define NPROJ   (DIM / 16)           // 320 projection blocks

typedef __attribute__((ext_vector_type(8))) short short8_t;
typedef __attribute__((ext_vector_type(4))) float floatx4;

// pack two f32x4 registers into a bf16x8 MFMA fragment
__device__ __forceinline__ short8_t pack8(const floatx4 f0, const floatx4 f1) {
    union { __hip_bfloat16 h[8]; short8_t v; } u;
    u.h[0] = __float2bfloat16(f0.x); u.h[1] = __float2bfloat16(f0.y);
    u.h[2] = __float2bfloat16(f0.z); u.h[3] = __float2bfloat16(f0.w);
    u.h[4] = __float2bfloat16(f1.x); u.h[5] = __float2bfloat16(f1.y);
    u.h[6] = __float2bfloat16(f1.z); u.h[7] = __float2bfloat16(f1.w);
    return u.v;
}
// cached load variant (vf is reused across blocks -> keep in L2)
__device__ __forceinline__ short8_t cvt8(const float* __restrict__ p) {
    return pack8(*reinterpret_cast<const floatx4*>(p),
                 *reinterpret_cast<const floatx4*>(p + 4));
}

// ---------------------------------------------------------------------------
// Single kernel, two roles, one dispatch, no workspace.
//   blocks [0, 320):    proj role. Prefetch this block's fc_w slice (no
//                       dependency on the scan), then scan text and compact
//                       the referenced vision rows (typically ~1 of 64),
//                       MFMA only those rows, write their 16 columns.
//   blocks [320, 1344): gather role. out[bt] = static table row, nontemporal,
//                       all loads issued before stores (MLP).
// ---------------------------------------------------------------------------
__global__ __launch_bounds__(256) void fused_kernel(
    const int*   __restrict__ text,   // [1024]
    const float* __restrict__ vf,     // [64][768]
    const float* __restrict__ fcw,    // [5120][768]
    const float* __restrict__ fcb,    // [5120]
    const float* __restrict__ weight, // [32000][5120]
    const float* __restrict__ fig,    // [2][5120]
    float*       __restrict__ out)    // [1024][5120]
{
    const int tid = threadIdx.x;

    if (blockIdx.x < NPROJ) {
        // ---- projection role ----
        __shared__ float sAcc[4][NROWS][17];      // +1 pad -> 2-way banks (free)
        __shared__ unsigned needMask[2];          // bitmap of needed rows
        __shared__ unsigned char rowList[NROWS];  // compacted slot -> row
        __shared__ unsigned char slotOf[NROWS];   // row -> slot
        __shared__ int visTok[NTOK];              // (t<<6)|r per vision token
        __shared__ int cntSh, nvSh;

        const int wave = tid >> 6;
        const int lane = tid & 63;
        const int l15  = lane & 15;
        const int lhi  = lane >> 4;
        const int d0   = blockIdx.x * 16;

        // wave's K range: [wave*192, +192), fragment k-offset lhi*8
        const int kbase = wave * 192 + lhi * 8;
        const float* wrow = &fcw[(size_t)(d0 + l15) * VDIM + kbase]; // HBM

        // prefetch the entire fc_w slice FIRST (independent of the scan);
        // the scan + barriers below hide the HBM latency of these 12 loads.
        floatx4 bf[12];
#pragma unroll
        for (int j = 0; j < 6; ++j) {
            const floatx4* p = reinterpret_cast<const floatx4*>(wrow + j * 32);
            bf[2 * j]     = __builtin_nontemporal_load(p);
            bf[2 * j + 1] = __builtin_nontemporal_load(p + 1);
        }

        if (tid < 2) needMask[tid] = 0u;
        if (tid == 0) nvSh = 0;
        __syncthreads();

        // scan token ids: mark needed rows, append vision-token list
        for (int t = tid; t < NTOK; t += 256) {
            const int idx = text[t];
            if (idx >= NSTATIC) {
                int vr = idx - NSTATIC;
                if (vr > TVIS - 1) vr = TVIS - 1;     // clip high (jnp.clip)
                const int r = (t >> 9) * TVIS + vr;   // b*32 + vr
                atomicOr(&needMask[r >> 5], 1u << (r & 31));
                visTok[atomicAdd(&nvSh, 1)] = (t << 6) | r;
            }
        }
        __syncthreads();
        if (tid == 0) {
            int c = 0;
            for (int r = 0; r < NROWS; ++r)
                if (needMask[r >> 5] & (1u << (r & 31))) {
                    rowList[c] = (unsigned char)r;
                    slotOf[r]  = (unsigned char)c;
                    ++c;
                }
            cntSh = c;
        }
        __syncthreads();
        const int cnt = cntSh;
        if (cnt == 0) return;                     // no vision tokens at all

        const int ngrp = (cnt + 15) >> 4;         // 16-row MFMA groups (<=4)

        int myrow[4];
#pragma unroll
        for (int g = 0; g < 4; ++g) {
            const int s = g * 16 + l15;
            myrow[g] = rowList[s < cnt ? s : 0];
        }

        floatx4 acc[4];
#pragma unroll
        for (int g = 0; g < 4; ++g) acc[g] = floatx4{0.f, 0.f, 0.f, 0.f};

#pragma unroll
        for (int j = 0; j < 6; ++j) {             // 6 chunks of k-32
            const short8_t b = pack8(bf[2 * j], bf[2 * j + 1]);
#pragma unroll
            for (int g = 0; g < 4; ++g) {         // block-uniform guard
                if (g < ngrp) {
                    const short8_t a = cvt8(&vf[(size_t)myrow[g] * VDIM + kbase + j * 32]);
                    acc[g] = __builtin_amdgcn_mfma_f32_16x16x32_bf16(a, b, acc[g], 0, 0, 0);
                }
            }
        }

        // C/D layout: col = lane&15 (-> d), row = (lane>>4)*4 + reg (-> slot)
#pragma unroll
        for (int g = 0; g < 4; ++g)
            if (g < ngrp)
#pragma unroll
                for (int rr = 0; rr < 4; ++rr)
                    sAcc[wave][g * 16 + lhi * 4 + rr][l15] = acc[g][rr];
        __syncthreads();

        // reduce K-partials + bias for live slots
        for (int o = tid; o < cnt * 16; o += 256) {
            const int s = o >> 4;
            const int d = o & 15;
            sAcc[0][s][d] = sAcc[0][s][d] + sAcc[1][s][d] +
                            sAcc[2][s][d] + sAcc[3][s][d] + fcb[d0 + d];
        }
        __syncthreads();

        // write our 16 columns for each vision token (16 threads per token)
        const int nv = nvSh;
        for (int e = tid >> 4; e < nv; e += 16) {
            const int pk = visTok[e];
            const int t  = pk >> 6;
            const int s  = slotOf[pk & 63];
            out[(size_t)t * DIM + d0 + (tid & 15)] = sAcc[0][s][tid & 15];
        }
    } else {
        // ---- static-token gather role ----
        const int bt  = blockIdx.x - NPROJ;
        const int idx = text[bt];
        if (idx >= NSTATIC) return;               // vision token: proj role owns it

        int r = idx < 0 ? 0 : idx;                // clip low (matches jnp.clip)
        const float* src = (r < VOCAB) ? &weight[(size_t)r * DIM]
                                       : &fig[(size_t)(r - VOCAB) * DIM];
        const floatx4* s4 = reinterpret_cast<const floatx4*>(src);
        floatx4*       d4 = reinterpret_cast<floatx4*>(&out[(size_t)bt * DIM]);

        // DIM/4 = 1280 = 5 * 256: fully unrolled, all loads before stores
        floatx4 v0 = __builtin_nontemporal_load(&s4[tid]);
        floatx4 v1 = __builtin_nontemporal_load(&s4[tid + 256]);
        floatx4 v2 = __builtin_nontemporal_load(&s4[tid + 512]);
        floatx4 v3 = __builtin_nontemporal_load(&s4[tid + 768]);
        floatx4 v4 = __builtin_nontemporal_load(&s4[tid + 1024]);
        __builtin_nontemporal_store(v0, &d4[tid]);
        __builtin_nontemporal_store(v1, &d4[tid + 256]);
        __builtin_nontemporal_store(v2, &d4[tid + 512]);
        __builtin_nontemporal_store(v3, &d4[tid + 768]);
        __builtin_nontemporal_store(v4, &d4[tid + 1024]);
    }
}

extern "C" void kernel_launch(void* const* d_in, const int* in_sizes, int n_in,
                              void* d_out, int out_size, void* d_ws, size_t ws_size,
                              hipStream_t stream) {
    (void)in_sizes; (void)n_in; (void)out_size; (void)d_ws; (void)ws_size;
    const int*   text = (const int*)  d_in[0];  // (B,T) int32
    const float* vf   = (const float*)d_in[1];  // (B,TV,VD)
    const float* w    = (const float*)d_in[2];  // (V,D)
    const float* fig  = (const float*)d_in[3];  // (2,D)
    const float* fcw  = (const float*)d_in[4];  // (D,VD)
    const float* fcb  = (const float*)d_in[5];  // (D,)
    float* out = (float*)d_out;                 // (B,T,D) f32

    fused_kernel<<<NPROJ + NTOK, 256, 0, stream>>>(
        text, vf, fcw, fcb, w, fig, out);
}

// Round 8
// 16.075 us; speedup vs baseline: 1.9081x; 1.0957x over previous
//
#include <hip/hip_runtime.h>
#include <hip/hip_bf16.h>

#define VOCAB   32000
#define DIM     5120
#define VDIM    768
#define BATCH   2
#define TLEN    512
#define NTOK    (BATCH * TLEN)       // 1024 tokens
#define TVIS    32
#define NSTATIC (VOCAB + 2)          // 32002
#define NROWS   (BATCH * TVIS)       // 64 possible vision rows
#define NPROJ   (DIM / 16)           // 320 projection blocks

typedef __attribute__((ext_vector_type(8))) short short8_t;
typedef __attribute__((ext_vector_type(4))) float floatx4;

// pack two f32x4 registers into a bf16x8 MFMA fragment
__device__ __forceinline__ short8_t pack8(const floatx4 f0, const floatx4 f1) {
    union { __hip_bfloat16 h[8]; short8_t v; } u;
    u.h[0] = __float2bfloat16(f0.x); u.h[1] = __float2bfloat16(f0.y);
    u.h[2] = __float2bfloat16(f0.z); u.h[3] = __float2bfloat16(f0.w);
    u.h[4] = __float2bfloat16(f1.x); u.h[5] = __float2bfloat16(f1.y);
    u.h[6] = __float2bfloat16(f1.z); u.h[7] = __float2bfloat16(f1.w);
    return u.v;
}
// cached load variant (vf is reused across blocks -> keep in L2)
__device__ __forceinline__ short8_t cvt8(const float* __restrict__ p) {
    return pack8(*reinterpret_cast<const floatx4*>(p),
                 *reinterpret_cast<const floatx4*>(p + 4));
}

// ---------------------------------------------------------------------------
// Single kernel, two roles, one dispatch, no workspace.
//   blocks [0, 320):    proj role. Prefetch this block's fc_w slice (hides
//                       under the text scan), compact the referenced vision
//                       rows wave-parallel (ballot/popc, no serial loop),
//                       MFMA only those rows, fold the 4-wave K-partial
//                       reduce into the vision-token write (one less barrier).
//   blocks [320, 1344): gather role. out[bt] = static table row, nontemporal,
//                       all 5 loads issued before the 5 stores (MLP).
// ---------------------------------------------------------------------------
__global__ __launch_bounds__(256) void fused_kernel(
    const int*   __restrict__ text,   // [1024]
    const float* __restrict__ vf,     // [64][768]
    const float* __restrict__ fcw,    // [5120][768]
    const float* __restrict__ fcb,    // [5120]
    const float* __restrict__ weight, // [32000][5120]
    const float* __restrict__ fig,    // [2][5120]
    float*       __restrict__ out)    // [1024][5120]
{
    const int tid = threadIdx.x;

    if (blockIdx.x < NPROJ) {
        // ---- projection role ----
        __shared__ float sAcc[4][NROWS][17];      // +1 pad -> 2-way banks (free)
        __shared__ unsigned needMask[2];          // bitmap of needed rows
        __shared__ unsigned char rowList[NROWS];  // compacted slot -> row
        __shared__ unsigned char slotOf[NROWS];   // row -> slot
        __shared__ int visTok[NTOK];              // (t<<6)|r per vision token
        __shared__ int cntSh, nvSh;

        const int wave = tid >> 6;
        const int lane = tid & 63;
        const int l15  = lane & 15;
        const int lhi  = lane >> 4;
        const int d0   = blockIdx.x * 16;

        // wave's K range: [wave*192, +192), fragment k-offset lhi*8
        const int kbase = wave * 192 + lhi * 8;
        const float* wrow = &fcw[(size_t)(d0 + l15) * VDIM + kbase]; // HBM

        // prefetch the entire fc_w slice FIRST (independent of the scan);
        // the scan + barriers below hide the HBM latency of these 12 loads.
        floatx4 bf[12];
#pragma unroll
        for (int j = 0; j < 6; ++j) {
            const floatx4* p = reinterpret_cast<const floatx4*>(wrow + j * 32);
            bf[2 * j]     = __builtin_nontemporal_load(p);
            bf[2 * j + 1] = __builtin_nontemporal_load(p + 1);
        }

        if (tid < 2) needMask[tid] = 0u;
        if (tid == 0) nvSh = 0;
        __syncthreads();

        // scan token ids: mark needed rows, append vision-token list
        for (int t = tid; t < NTOK; t += 256) {
            const int idx = text[t];
            if (idx >= NSTATIC) {
                int vr = idx - NSTATIC;
                if (vr > TVIS - 1) vr = TVIS - 1;     // clip high (jnp.clip)
                const int r = (t >> 9) * TVIS + vr;   // b*32 + vr
                atomicOr(&needMask[r >> 5], 1u << (r & 31));
                visTok[atomicAdd(&nvSh, 1)] = (t << 6) | r;
            }
        }
        __syncthreads();

        // wave-parallel compaction (wave 0): lane r owns row r
        if (tid < 64) {
            const unsigned long long m64 =
                ((unsigned long long)needMask[1] << 32) | needMask[0];
            const unsigned long long below = (tid == 0)
                ? 0ull : (m64 & ((1ull << tid) - 1ull));
            const int slot = (int)__popcll(below);
            if ((m64 >> tid) & 1ull) {
                rowList[slot] = (unsigned char)tid;
                slotOf[tid]   = (unsigned char)slot;
            }
            if (tid == 0) cntSh = (int)__popcll(m64);
        }
        __syncthreads();
        const int cnt = cntSh;
        if (cnt == 0) return;                     // no vision tokens at all

        const int ngrp = (cnt + 15) >> 4;         // 16-row MFMA groups (<=4)

        int myrow[4];
#pragma unroll
        for (int g = 0; g < 4; ++g) {
            const int s = g * 16 + l15;
            myrow[g] = rowList[s < cnt ? s : 0];
        }

        floatx4 acc[4];
#pragma unroll
        for (int g = 0; g < 4; ++g) acc[g] = floatx4{0.f, 0.f, 0.f, 0.f};

#pragma unroll
        for (int j = 0; j < 6; ++j) {             // 6 chunks of k-32
            const short8_t b = pack8(bf[2 * j], bf[2 * j + 1]);
#pragma unroll
            for (int g = 0; g < 4; ++g) {         // block-uniform guard
                if (g < ngrp) {
                    const short8_t a = cvt8(&vf[(size_t)myrow[g] * VDIM + kbase + j * 32]);
                    acc[g] = __builtin_amdgcn_mfma_f32_16x16x32_bf16(a, b, acc[g], 0, 0, 0);
                }
            }
        }

        // C/D layout: col = lane&15 (-> d), row = (lane>>4)*4 + reg (-> slot)
#pragma unroll
        for (int g = 0; g < 4; ++g)
            if (g < ngrp)
#pragma unroll
                for (int rr = 0; rr < 4; ++rr)
                    sAcc[wave][g * 16 + lhi * 4 + rr][l15] = acc[g][rr];
        __syncthreads();

        // write our 16 columns for each vision token, folding the 4-wave
        // K-partial reduce + bias into the write (no separate pass/barrier)
        const int nv = nvSh;
        const int dcol = tid & 15;
        const float bias = fcb[d0 + dcol];
        for (int e = tid >> 4; e < nv; e += 16) {
            const int pk = visTok[e];
            const int t  = pk >> 6;
            const int s  = slotOf[pk & 63];
            const float v = sAcc[0][s][dcol] + sAcc[1][s][dcol] +
                            sAcc[2][s][dcol] + sAcc[3][s][dcol] + bias;
            out[(size_t)t * DIM + d0 + dcol] = v;
        }
    } else {
        // ---- static-token gather role ----
        const int bt  = blockIdx.x - NPROJ;
        const int idx = text[bt];
        if (idx >= NSTATIC) return;               // vision token: proj role owns it

        int r = idx < 0 ? 0 : idx;                // clip low (matches jnp.clip)
        const float* src = (r < VOCAB) ? &weight[(size_t)r * DIM]
                                       : &fig[(size_t)(r - VOCAB) * DIM];
        const floatx4* s4 = reinterpret_cast<const floatx4*>(src);
        floatx4*       d4 = reinterpret_cast<floatx4*>(&out[(size_t)bt * DIM]);

        // DIM/4 = 1280 = 5 * 256: fully unrolled, all loads before stores
        floatx4 v0 = __builtin_nontemporal_load(&s4[tid]);
        floatx4 v1 = __builtin_nontemporal_load(&s4[tid + 256]);
        floatx4 v2 = __builtin_nontemporal_load(&s4[tid + 512]);
        floatx4 v3 = __builtin_nontemporal_load(&s4[tid + 768]);
        floatx4 v4 = __builtin_nontemporal_load(&s4[tid + 1024]);
        __builtin_nontemporal_store(v0, &d4[tid]);
        __builtin_nontemporal_store(v1, &d4[tid + 256]);
        __builtin_nontemporal_store(v2, &d4[tid + 512]);
        __builtin_nontemporal_store(v3, &d4[tid + 768]);
        __builtin_nontemporal_store(v4, &d4[tid + 1024]);
    }
}

extern "C" void kernel_launch(void* const* d_in, const int* in_sizes, int n_in,
                              void* d_out, int out_size, void* d_ws, size_t ws_size,
                              hipStream_t stream) {
    (void)in_sizes; (void)n_in; (void)out_size; (void)d_ws; (void)ws_size;
    const int*   text = (const int*)  d_in[0];  // (B,T) int32
    const float* vf   = (const float*)d_in[1];  // (B,TV,VD)
    const float* w    = (const float*)d_in[2];  // (V,D)
    const float* fig  = (const float*)d_in[3];  // (2,D)
    const float* fcw  = (const float*)d_in[4];  // (D,VD)
    const float* fcb  = (const float*)d_in[5];  // (D,)
    float* out = (float*)d_out;                 // (B,T,D) f32

    fused_kernel<<<NPROJ + NTOK, 256, 0, stream>>>(
        text, vf, fcw, fcb, w, fig, out);
}